// Round 1
// baseline (348.924 us; speedup 1.0000x reference)
//
#include <hip/hip_runtime.h>
#include <hip/hip_bf16.h>

#define DIM 128
#define KNB 16

// ---------------------------------------------------------------------------
// Phase 1: AB precompute.  A[n][h] = b1[h] + sum_d lat[n][d]*W1[d][h]
//                          B[n][h] =         sum_d lat[n][d]*W1[128+d][h]
// Block = 256 threads, 32 nodes per block. Latents staged transposed in LDS
// ([128][36] pad -> bank-conflict-free writes, 16B-aligned b128 reads).
// Thread t owns one output column c (c<128 -> A, else B), 32 accumulators.
// ---------------------------------------------------------------------------
__global__ __launch_bounds__(256) void na_precompute_AB(
    const float* __restrict__ lat, const float* __restrict__ W1,
    const float* __restrict__ b1, float* __restrict__ A,
    float* __restrict__ B, int nNodes)
{
    __shared__ float lt[DIM][36];   // transposed latent tile, 18 KiB
    const int t = threadIdx.x;
    const int base = blockIdx.x * 32;

#pragma unroll
    for (int i = 0; i < 16; ++i) {
        int idx = i * 256 + t;          // 0..4095
        int nl  = idx >> 7;             // local node 0..31
        int d   = idx & 127;
        int n   = base + nl;
        float v = (n < nNodes) ? lat[(size_t)n * DIM + d] : 0.f;
        lt[d][nl] = v;
    }
    __syncthreads();

    const int c   = t;                  // 0..255
    const int h   = c & 127;
    const int isB = c >> 7;
    const float* wcol = W1 + (size_t)(isB ? DIM : 0) * DIM + h;

    float acc[32];
#pragma unroll
    for (int i = 0; i < 32; ++i) acc[i] = 0.f;

    for (int d = 0; d < DIM; ++d) {
        float w = wcol[(size_t)d * DIM];
#pragma unroll
        for (int i = 0; i < 32; ++i) acc[i] += lt[d][i] * w;
    }

    float bias = isB ? 0.f : b1[h];
    float* dst = isB ? B : A;
#pragma unroll
    for (int i = 0; i < 32; ++i) {
        int n = base + i;
        if (n < nNodes) dst[(size_t)n * DIM + h] = acc[i] + bias;
    }
}

// ---------------------------------------------------------------------------
// Phase 2: per-node scores + softmax + weighted aggregation.
// One wave (64 lanes) per node; lane l owns dims l and l+64.
// score_k = dot(relu(A[n] + B[j_k]), W2)   (b2 cancels in softmax)
// out[n]  = sum_k softmax(score)_k * lat[j_k]
// ---------------------------------------------------------------------------
__global__ __launch_bounds__(256) void na_score_agg(
    const float* __restrict__ lat, const int* __restrict__ nbr,
    const float* __restrict__ A, const float* __restrict__ B,
    const float* __restrict__ W2, float* __restrict__ out, int nNodes)
{
    const int wave = threadIdx.x >> 6;
    const int lane = threadIdx.x & 63;
    const int n = blockIdx.x * 4 + wave;
    if (n >= nNodes) return;

    const int d0 = lane, d1 = lane + 64;
    const float a0  = A[(size_t)n * DIM + d0];
    const float a1  = A[(size_t)n * DIM + d1];
    const float w20 = W2[d0];
    const float w21 = W2[d1];

    const int jl = nbr[n * KNB + (lane & 15)];   // 16 idx spread over lanes

    float s[KNB], nl0[KNB], nl1[KNB];

#pragma unroll
    for (int k = 0; k < KNB; ++k) {
        int j = __shfl(jl, k);
        const float* Bj = B   + (size_t)j * DIM;
        const float* Lj = lat + (size_t)j * DIM;
        float b0v = Bj[d0];
        float b1v = Bj[d1];
        float l0  = Lj[d0];
        float l1  = Lj[d1];
        nl0[k] = l0; nl1[k] = l1;
        float h0 = fmaxf(a0 + b0v, 0.f);
        float h1 = fmaxf(a1 + b1v, 0.f);
        float p  = h0 * w20 + h1 * w21;
#pragma unroll
        for (int off = 32; off; off >>= 1) p += __shfl_xor(p, off);
        s[k] = p;
    }

    // softmax over 16 scores (identical across lanes)
    float m = s[0];
#pragma unroll
    for (int k = 1; k < KNB; ++k) m = fmaxf(m, s[k]);
    float sum = 0.f;
#pragma unroll
    for (int k = 0; k < KNB; ++k) { s[k] = expf(s[k] - m); sum += s[k]; }
    float inv = 1.f / sum;

    float o0 = 0.f, o1 = 0.f;
#pragma unroll
    for (int k = 0; k < KNB; ++k) { o0 += s[k] * nl0[k]; o1 += s[k] * nl1[k]; }

    out[(size_t)n * DIM + d0] = o0 * inv;
    out[(size_t)n * DIM + d1] = o1 * inv;
}

// ---------------------------------------------------------------------------
// Fallback (only if workspace too small): direct computation, one wave/node.
// ---------------------------------------------------------------------------
__global__ __launch_bounds__(256) void na_naive(
    const float* __restrict__ lat, const int* __restrict__ nbr,
    const float* __restrict__ W1, const float* __restrict__ b1,
    const float* __restrict__ W2, float* __restrict__ out, int nNodes)
{
    const int wave = threadIdx.x >> 6;
    const int lane = threadIdx.x & 63;
    const int n = blockIdx.x * 4 + wave;
    if (n >= nNodes) return;

    const int d0 = lane, d1 = lane + 64;
    const float w20 = W2[d0];
    const float w21 = W2[d1];
    const float c0 = lat[(size_t)n * DIM + d0];
    const float c1 = lat[(size_t)n * DIM + d1];

    // a = b1 + central @ W1_top  (per-node, reused across k)
    float a0 = b1[d0], a1 = b1[d1];
    for (int r = 0; r < DIM; ++r) {
        float cv = (r < 64) ? __shfl(c0, r) : __shfl(c1, r - 64);
        a0 += cv * W1[(size_t)r * DIM + d0];
        a1 += cv * W1[(size_t)r * DIM + d1];
    }

    const int jl = nbr[n * KNB + (lane & 15)];
    float s[KNB], nl0[KNB], nl1[KNB];

    for (int k = 0; k < KNB; ++k) {
        int j = __shfl(jl, k);
        float l0 = lat[(size_t)j * DIM + d0];
        float l1 = lat[(size_t)j * DIM + d1];
        nl0[k] = l0; nl1[k] = l1;
        float h0 = a0, h1 = a1;
        for (int r = 0; r < DIM; ++r) {
            float nv = (r < 64) ? __shfl(l0, r) : __shfl(l1, r - 64);
            h0 += nv * W1[(size_t)(DIM + r) * DIM + d0];
            h1 += nv * W1[(size_t)(DIM + r) * DIM + d1];
        }
        h0 = fmaxf(h0, 0.f);
        h1 = fmaxf(h1, 0.f);
        float p = h0 * w20 + h1 * w21;
#pragma unroll
        for (int off = 32; off; off >>= 1) p += __shfl_xor(p, off);
        s[k] = p;
    }

    float m = s[0];
#pragma unroll
    for (int k = 1; k < KNB; ++k) m = fmaxf(m, s[k]);
    float sum = 0.f;
#pragma unroll
    for (int k = 0; k < KNB; ++k) { s[k] = expf(s[k] - m); sum += s[k]; }
    float inv = 1.f / sum;

    float o0 = 0.f, o1 = 0.f;
#pragma unroll
    for (int k = 0; k < KNB; ++k) { o0 += s[k] * nl0[k]; o1 += s[k] * nl1[k]; }

    out[(size_t)n * DIM + d0] = o0 * inv;
    out[(size_t)n * DIM + d1] = o1 * inv;
}

extern "C" void kernel_launch(void* const* d_in, const int* in_sizes, int n_in,
                              void* d_out, int out_size, void* d_ws, size_t ws_size,
                              hipStream_t stream)
{
    const float* lat = (const float*)d_in[0];
    const int*   nbr = (const int*)  d_in[1];
    const float* W1  = (const float*)d_in[2];
    const float* b1  = (const float*)d_in[3];
    const float* W2  = (const float*)d_in[4];
    // d_in[5] = b2: shift-invariant under softmax, unused.
    float* out = (float*)d_out;

    const int nNodes = in_sizes[0] / DIM;                       // 100000
    const size_t need = (size_t)nNodes * DIM * 2 * sizeof(float); // A+B, 102.4 MB

    if (ws_size >= need) {
        float* A = (float*)d_ws;
        float* B = A + (size_t)nNodes * DIM;
        na_precompute_AB<<<(nNodes + 31) / 32, 256, 0, stream>>>(lat, W1, b1, A, B, nNodes);
        na_score_agg<<<(nNodes + 3) / 4, 256, 0, stream>>>(lat, nbr, A, B, W2, out, nNodes);
    } else {
        na_naive<<<(nNodes + 3) / 4, 256, 0, stream>>>(lat, nbr, W1, b1, W2, out, nNodes);
    }
}